// Round 8
// baseline (229.008 us; speedup 1.0000x reference)
//
#include <hip/hip_runtime.h>

// ---- types -----------------------------------------------------------------
typedef __bf16 bf16;
typedef __attribute__((ext_vector_type(8))) __bf16 bf16x8;
typedef __attribute__((ext_vector_type(4))) __bf16 bf16x4;
typedef __attribute__((ext_vector_type(4))) float  f32x4;

static __device__ __forceinline__ f32x4 mfma16(bf16x8 a, bf16x8 b, f32x4 c) {
  return __builtin_amdgcn_mfma_f32_16x16x32_bf16(a, b, c, 0, 0, 0);
}
static __device__ __forceinline__ float fexp2(float x) {
  return __builtin_amdgcn_exp2f(x);
}

// exp(s/sqrt(128)) = exp2(s * C1)
#define EXP_C1 (1.4426950408889634f / 11.313708498984760f)

// async global->LDS, 16B/lane; dst base is wave-uniform, HW adds lane*16.
typedef const __attribute__((address_space(1))) unsigned int gas_u32;
typedef __attribute__((address_space(3))) unsigned int las_u32;
#define GLDS16(gp, lp) __builtin_amdgcn_global_load_lds((gas_u32*)(gp), (las_u32*)(lp), 16, 0, 0)

// RACE FIX (r4->r5, keep): drain own vmcnt BEFORE s_barrier so cross-wave
// DMA completion is guaranteed.
#define DMA_FENCE() __asm__ volatile("s_waitcnt vmcnt(0)" ::: "memory")

// Granule-major tile (128 rows x 128 cols bf16, 32KB): elem(r,c) = (c>>3)*1024 + r*8 + (c&7).
// V is ROW-PERMUTED (k_qkv epilogue) so PV consumes the QK^T C-fragment from
// registers: slot (quad,e) of 32-block s holds V row k = 32s + quad*4 + (e&3) + 16*(e>>2).
// XCD swizzle (keep): grids (64 b, ...) with b on X -> same-b blocks share an XCD L2.
//
// R7->R8 (LDS-pipe split): k_attn was LDS-read-bound at 1 KB ds_read per MFMA
// (2.1M MFMA x 1KB / 256 CU / 85 B/cyc = 41 us = measured). Now K-frags stay
// on the LDS pipe, V-frags come from direct global (L1/L2-served; V-tile is
// identical across the block's 8 waves and XCD-L2-resident) -> LDS traffic
// halves. k_stats: two-stage q-split -> 32 k-rows/wave in regs (each Q-frag
// read feeds 2 MFMA) at unchanged 16 waves/CU.

// ============================================================================
// Kernel 0: prep. W[3][128][256] fp32 -> Wc[3][32 g][128 n][8] bf16.
// ============================================================================
__global__ __launch_bounds__(256) void k_prep(
    const float* __restrict__ Wq, const float* __restrict__ Wk,
    const float* __restrict__ Wv, bf16* __restrict__ Wc)
{
  int id = blockIdx.x * 256 + threadIdx.x;      // 48 blocks = 3*4096
  int proj = id >> 12, r = id & 4095;
  int g = r >> 7, n = r & 127;
  const float* W = proj == 0 ? Wq : proj == 1 ? Wk : Wv;
  const float4* src = (const float4*)(W + n * 256 + g * 8);
  float4 a = src[0], b = src[1];
  bf16x8 o = { (bf16)a.x, (bf16)a.y, (bf16)a.z, (bf16)a.w,
               (bf16)b.x, (bf16)b.y, (bf16)b.z, (bf16)b.w };
  *(bf16x8*)(Wc + (size_t)proj * 32768 + g * 1024 + n * 8) = o;
}

// ============================================================================
// Kernel 1: QKV projection (unchanged from r7). grid(1024) 64-row tiles,
// block 256, 4 blocks/CU. Q/K swapped operands -> packed bf16x4 stores.
// ============================================================================
__global__ __launch_bounds__(256, 4) void k_qkv(
    const float* __restrict__ q, const bf16* __restrict__ Wc,
    const float* __restrict__ bq, const float* __restrict__ bk, const float* __restrict__ bv,
    bf16* __restrict__ Qb, bf16* __restrict__ Kb, bf16* __restrict__ VT)
{
  __shared__ bf16 Al[32 * 520];                 // 32 granules x (64 rows x 8 + 8 pad)

  const int tid = threadIdx.x, lane = tid & 63, wave = tid >> 6;
  const int ln = lane & 15, quad = lane >> 4;
  const int sh = wave & 1, dh = wave >> 1;      // 32-s half, 64-d half
  const int m0 = blockIdx.x * 64;

  { // stage: 16 coalesced float4/thread -> bf16 chunks
    const float* src = q + (size_t)m0 * 256;
    for (int it = 0; it < 16; ++it) {
      int f = it * 1024 + tid * 4;
      int r = f >> 8, c = f & 255;
      float4 v = *(const float4*)(src + f);
      bf16x4 o = { (bf16)v.x, (bf16)v.y, (bf16)v.z, (bf16)v.w };
      *(bf16x4*)&Al[(c >> 3) * 520 + r * 8 + (c & 7)] = o;
    }
  }
  __syncthreads();

  const int b = m0 >> 10, st = (m0 & 1023) >> 7, s64 = m0 & 64;
  const size_t tbase = ((size_t)b * 8 + st) * 16384;

  for (int p = 0; p < 2; ++p) {                 // Q, K: D[d][s], A=W
    const bf16* W = Wc + (size_t)p * 32768;
    const float* bias = p == 0 ? bq : bk;
    f32x4 acc[4][2] = {};
    for (int kk = 0; kk < 8; ++kk) {
      int g = kk * 4 + quad;
      bf16x8 ax[2], bw[4];
      for (int j = 0; j < 2; ++j)
        ax[j] = *(const bf16x8*)&Al[g * 520 + (sh * 32 + j * 16 + ln) * 8];
      for (int i = 0; i < 4; ++i)
        bw[i] = *(const bf16x8*)(W + g * 1024 + (dh * 64 + i * 16 + ln) * 8);
      for (int i = 0; i < 4; ++i)
        for (int j = 0; j < 2; ++j)
          acc[i][j] = mfma16(bw[i], ax[j], acc[i][j]);
    }
    bf16* dst = (p == 0 ? Qb : Kb) + tbase;
    for (int i = 0; i < 4; ++i) {
      float4 b4 = *(const float4*)&bias[dh * 64 + i * 16 + quad * 4];
      int gd = dh * 8 + i * 2 + (quad >> 1);
      int e0 = (quad & 1) * 4;
      for (int j = 0; j < 2; ++j) {
        int s = s64 + sh * 32 + j * 16 + ln;
        bf16x4 o = { (bf16)(acc[i][j][0] + b4.x), (bf16)(acc[i][j][1] + b4.y),
                     (bf16)(acc[i][j][2] + b4.z), (bf16)(acc[i][j][3] + b4.w) };
        *(bf16x4*)&dst[(size_t)gd * 1024 + (size_t)s * 8 + e0] = o;
      }
    }
  }
  {                                             // V: D[s][d], row-permuted store
    const bf16* W = Wc + (size_t)2 * 32768;
    f32x4 acc[2][4] = {};
    for (int kk = 0; kk < 8; ++kk) {
      int g = kk * 4 + quad;
      bf16x8 ax[2], bw[4];
      for (int i = 0; i < 2; ++i)
        ax[i] = *(const bf16x8*)&Al[g * 520 + (sh * 32 + i * 16 + ln) * 8];
      for (int j = 0; j < 4; ++j)
        bw[j] = *(const bf16x8*)(W + g * 1024 + (dh * 64 + j * 16 + ln) * 8);
      for (int i = 0; i < 2; ++i)
        for (int j = 0; j < 4; ++j)
          acc[i][j] = mfma16(ax[i], bw[j], acc[i][j]);
    }
    bf16* dst = VT + tbase;
    for (int j = 0; j < 4; ++j) {
      int d = dh * 64 + j * 16 + ln;
      float bb = bv[d];
      for (int i = 0; i < 2; ++i) {
        int s0 = s64 + sh * 32 + i * 16 + quad * 4;
        int G  = (s0 >> 5) * 4 + ((s0 & 15) >> 2);
        int e0 = (s0 & 16) >> 2;
        bf16x4 o = { (bf16)(acc[i][j][0] + bb), (bf16)(acc[i][j][1] + bb),
                     (bf16)(acc[i][j][2] + bb), (bf16)(acc[i][j][3] + bb) };
        *(bf16x4*)&dst[(size_t)G * 1024 + (size_t)d * 8 + e0] = o;
      }
    }
  }
}

// ============================================================================
// Kernel 2a: partial column sums. grid(64 b, 4 kt2, 2 qh), block 512
// (8 waves x 32 k-rows in REGISTERS -> each Q-frag LDS read feeds 2 MFMA).
// q split in halves across blocks -> 16 waves/CU retained. Partial sums to
// psum[qh][b][1024]; combined by k_inv.
// ============================================================================
__global__ __launch_bounds__(512, 4) void k_stats_p(
    const bf16* __restrict__ Qb, const bf16* __restrict__ Kb, float* __restrict__ psum)
{
  __shared__ char Qbuf[2][32768];
  const int b = blockIdx.x, kt2 = blockIdx.y, qh = blockIdx.z;
  const int tid = threadIdx.x, lane = tid & 63, wave = tid >> 6;   // wave 0..7
  const int ln = lane & 15, quad = lane >> 4;

  const int k0 = kt2 * 256 + wave * 32;
  const bf16* ktile = Kb + ((size_t)b * 8 + (k0 >> 7)) * 16384;
  const int kr = k0 & 127;
  bf16x8 ak[2][4];                              // wave's 32 k-rows, full d=128
  for (int i = 0; i < 2; ++i)
    for (int kk = 0; kk < 4; ++kk)
      ak[i][kk] = *(const bf16x8*)(ktile + (kk * 4 + quad) * 1024 + (kr + i * 16 + ln) * 8);

  const char* qb_b = (const char*)(Qb + (size_t)b * 8 * 16384) + (size_t)qh * 4 * 32768;
  for (int c = 0; c < 4; ++c) {                 // prologue DMA q-tile 0
    int ch = wave * 4 + c;
    GLDS16(qb_b + ch * 1024 + lane * 16, &Qbuf[0][ch * 1024]);
  }

  f32x4 csum[2] = {};
  for (int qti = 0; qti < 4; ++qti) {
    DMA_FENCE();
    __syncthreads();                            // all waves' DMA(qti) complete
    if (qti < 3)
      for (int c = 0; c < 4; ++c) {
        int ch = wave * 4 + c;
        GLDS16(qb_b + (size_t)(qti + 1) * 32768 + ch * 1024 + lane * 16,
               &Qbuf[(qti + 1) & 1][ch * 1024]);
      }
    const char* Ql = Qbuf[qti & 1];
    for (int jq = 0; jq < 8; ++jq) {
      f32x4 s0 = {}, s1 = {};
      for (int kk = 0; kk < 4; ++kk) {
        bf16x8 bqf = *(const bf16x8*)(Ql + ((kk * 4 + quad) * 2 + (jq >> 2)) * 1024
                                         + ((jq * 16 + ln) & 63) * 16);
        s0 = mfma16(ak[0][kk], bqf, s0);
        s1 = mfma16(ak[1][kk], bqf, s1);
      }
      for (int rr = 0; rr < 4; ++rr) {
        csum[0][rr] += fexp2(s0[rr] * EXP_C1);
        csum[1][rr] += fexp2(s1[rr] * EXP_C1);
      }
    }
  }
  for (int i = 0; i < 2; ++i)
    for (int rr = 0; rr < 4; ++rr) {            // reduce over 16 q-cols (lanes)
      float v = csum[i][rr];
      v += __shfl_xor(v, 1, 64); v += __shfl_xor(v, 2, 64);
      v += __shfl_xor(v, 4, 64); v += __shfl_xor(v, 8, 64);
      csum[i][rr] = v;
    }
  if (ln == 0) {
    float* dst = psum + (size_t)qh * 65536 + (size_t)b * 1024 + k0 + quad * 4;
    for (int i = 0; i < 2; ++i)
      for (int rr = 0; rr < 4; ++rr)
        dst[i * 16 + rr] = csum[i][rr];
  }
}

// ============================================================================
// Kernel 2b: combine halves -> inv[b][k] = 1/(p0+p1).
// ============================================================================
__global__ __launch_bounds__(256) void k_inv(
    const float* __restrict__ psum, float* __restrict__ inv)
{
  int i = blockIdx.x * 256 + threadIdx.x;       // 65536
  inv[i] = 1.0f / (psum[i] + psum[65536 + i]);
}

// ============================================================================
// Kernel 3: fused S^T=K Q^T -> P=exp*inv (in regs) -> O += P Vc -> q-max.
// grid(64 b, 8 qt), block 512 (8 waves x 16 q-rows, each wave full 64 k),
// 2 blocks/CU = 16 waves/CU. K via double-buffered LDS DMA (LDS pipe);
// V-frags DIRECT FROM GLOBAL (L1/L2 pipe, same addrs across the 8 waves,
// XCD-L2-resident) -> LDS read traffic per MFMA halves.
// ============================================================================
__global__ __launch_bounds__(512, 4) void k_attn(
    const bf16* __restrict__ Qb, const bf16* __restrict__ Kb, const bf16* __restrict__ VT,
    const float* __restrict__ inv, float* __restrict__ Opart)
{
  __shared__ char buf[2][16384];                // K-tile double buffer
  __shared__ float invl[1024];
  __shared__ float redm[8][128];

  const int b = blockIdx.x, qt = blockIdx.y;
  const int tid = threadIdx.x, lane = tid & 63, wave = tid >> 6;   // wave 0..7
  const int ln = lane & 15, quad = lane >> 4;

  *(float2*)&invl[tid * 2] = *(const float2*)(inv + (size_t)b * 1024 + tid * 2);

  const bf16* qtile = Qb + ((size_t)b * 8 + qt) * 16384;
  bf16x8 bq_[4];                                // wave's 16 q-rows, full d
  for (int kk = 0; kk < 4; ++kk)
    bq_[kk] = *(const bf16x8*)(qtile + (kk * 4 + quad) * 1024 + (wave * 16 + ln) * 8);

  const char* kb_b = (const char*)(Kb + (size_t)b * 8 * 16384);
  const char* vt_b = (const char*)(VT + (size_t)b * 8 * 16384);

#define DMA_K(t) do {                                                            \
    const char* ksrc = kb_b + (size_t)((t) >> 1) * 32768 + ((t) & 1) * 1024;     \
    char* d_ = buf[(t) & 1];                                                     \
    for (int c = 0; c < 2; ++c) {                                                \
      int ch = wave * 2 + c;                                                     \
      GLDS16(ksrc + ch * 2048 + lane * 16, d_ + ch * 1024);                      \
    }                                                                            \
  } while (0)

  f32x4 oacc[8] = {};
  DMA_K(0);

  for (int t = 0; t < 16; ++t) {
    DMA_FENCE();
    __syncthreads();                            // all waves' K-DMA(t) complete
    if (t < 15) DMA_K(t + 1);
    const char* Kl = buf[t & 1];
    const char* vtile = vt_b + (size_t)(t >> 1) * 32768 + (t & 1) * 16384;

    // V-frags (s=0 half) from global, issued BEFORE QK so L2 latency is
    // covered by the QK phase.
    bf16x8 vf[8];
    for (int j2 = 0; j2 < 8; ++j2)
      vf[j2] = *(const bf16x8*)(vtile + (quad * 2 + (j2 >> 2)) * 1024
                                       + ((j2 * 16 + ln) & 63) * 16);

    // S^T = K Q^T : 64 k x wave's 16 q. 16 MFMA, 16 LDS reads.
    f32x4 sacc[4] = {};
    for (int kk = 0; kk < 4; ++kk) {
      for (int i = 0; i < 4; ++i) {
        bf16x8 akf = *(const bf16x8*)(Kl + (kk * 4 + quad) * 1024 + (i * 16 + ln) * 16);
        sacc[i] = mfma16(akf, bq_[kk], sacc[i]);
      }
    }
    // P = exp2(S*C1)*inv[k] -> PV A-frags in regs
    // (element e of step s: k = 32s + quad*4 + (e&3) + 16*(e>>2)).
    bf16x8 pf[2];
    for (int s = 0; s < 2; ++s) {
      float4 iv0 = *(float4*)&invl[t * 64 + (2 * s) * 16 + quad * 4];
      float4 iv1 = *(float4*)&invl[t * 64 + (2 * s + 1) * 16 + quad * 4];
      f32x4 lo = sacc[2 * s], hi = sacc[2 * s + 1];
      pf[s] = bf16x8{
        (bf16)(fexp2(lo[0] * EXP_C1) * iv0.x), (bf16)(fexp2(lo[1] * EXP_C1) * iv0.y),
        (bf16)(fexp2(lo[2] * EXP_C1) * iv0.z), (bf16)(fexp2(lo[3] * EXP_C1) * iv0.w),
        (bf16)(fexp2(hi[0] * EXP_C1) * iv1.x), (bf16)(fexp2(hi[1] * EXP_C1) * iv1.y),
        (bf16)(fexp2(hi[2] * EXP_C1) * iv1.z), (bf16)(fexp2(hi[3] * EXP_C1) * iv1.w) };
    }
    // O += P @ Vc : s=0 with prefetched vf, then reload vf with s=1 half.
    for (int j2 = 0; j2 < 8; ++j2)
      oacc[j2] = mfma16(pf[0], vf[j2], oacc[j2]);
    for (int j2 = 0; j2 < 8; ++j2)
      vf[j2] = *(const bf16x8*)(vtile + ((4 + quad) * 2 + (j2 >> 2)) * 1024
                                       + ((j2 * 16 + ln) & 63) * 16);
    for (int j2 = 0; j2 < 8; ++j2)
      oacc[j2] = mfma16(pf[1], vf[j2], oacc[j2]);
  }

  // max over this block's 128 q rows, per output column d
  for (int j2 = 0; j2 < 8; ++j2) {
    float m = fmaxf(fmaxf(oacc[j2][0], oacc[j2][1]), fmaxf(oacc[j2][2], oacc[j2][3]));
    m = fmaxf(m, __shfl_xor(m, 16, 64));
    m = fmaxf(m, __shfl_xor(m, 32, 64));
    if (lane < 16) redm[wave][j2 * 16 + ln] = m;
  }
  __syncthreads();
  if (tid < 128) {
    float m = redm[0][tid];
    for (int w = 1; w < 8; ++w) m = fmaxf(m, redm[w][tid]);
    Opart[((size_t)b * 8 + qt) * 128 + tid] = m;
  }
}

// ============================================================================
// Kernel 4: final 8-way max over q-tiles -> d_out [64,128] fp32
// ============================================================================
__global__ __launch_bounds__(256) void k_final(
    const float* __restrict__ Opart, float* __restrict__ out)
{
  int t = blockIdx.x * 256 + threadIdx.x;       // 8192 outputs
  int b = t >> 7, d = t & 127;
  const float* p = Opart + (size_t)b * 1024 + d;
  float m = p[0];
  for (int i = 1; i < 8; ++i) m = fmaxf(m, p[(size_t)i * 128]);
  out[t] = m;
}

// ============================================================================
extern "C" void kernel_launch(void* const* d_in, const int* in_sizes, int n_in,
                              void* d_out, int out_size, void* d_ws, size_t ws_size,
                              hipStream_t stream) {
  const float* q  = (const float*)d_in[0];
  const float* Wq = (const float*)d_in[1];
  const float* bq = (const float*)d_in[2];
  const float* Wk = (const float*)d_in[3];
  const float* bk = (const float*)d_in[4];
  const float* Wv = (const float*)d_in[5];
  const float* bv = (const float*)d_in[6];
  float* out = (float*)d_out;

  char* ws = (char*)d_ws;
  bf16*  Qb    = (bf16*)(ws);                               // 16 MB granule tiles [s][d]
  bf16*  Kb    = (bf16*)(ws + (16u << 20));                 // 16 MB
  bf16*  VT    = (bf16*)(ws + (32u << 20));                 // 16 MB (V^T, row-permuted)
  float* inv   = (float*)(ws + (48u << 20));                // 256 KB [64][1024]
  float* Opart = (float*)(ws + (48u << 20) + (256u << 10)); // 256 KB [64][8][128]
  float* psum  = (float*)(ws + (48u << 20) + (512u << 10)); // 512 KB [2][64][1024]
  bf16*  Wc    = (bf16*)(ws + (49u << 20));                 // 192 KB [3][32][128][8]

  k_prep   <<<48,              256, 0, stream>>>(Wq, Wk, Wv, Wc);
  k_qkv    <<<dim3(1024),      256, 0, stream>>>(q, Wc, bq, bk, bv, Qb, Kb, VT);
  k_stats_p<<<dim3(64, 4, 2),  512, 0, stream>>>(Qb, Kb, psum);
  k_inv    <<<256,             256, 0, stream>>>(psum, inv);
  k_attn   <<<dim3(64, 8),     512, 0, stream>>>(Qb, Kb, VT, inv, Opart);
  k_final  <<<32,              256, 0, stream>>>(Opart, out);
}